// Round 1
// baseline (2217.960 us; speedup 1.0000x reference)
//
#include <hip/hip_runtime.h>
#include <cstdint>
#include <cstddef>

// Problem dims (RNN_57208964382771)
#define Bz 64
#define Tz 2048
#define Hz 8
#define Vz 1000
#define Oz 1000

// 2/ln2 — folded into W_hh and x_proj so fast_tanh skips its input scaling mul
#define SCALE 2.885390081777927f

typedef float f32x4 __attribute__((ext_vector_type(4)));
typedef float f32x2 __attribute__((ext_vector_type(2)));

// ---------------------------------------------------------------------------
// Kernel 1: xpT[b][q][t][e] = (dot(emb[X[b,t]], W_ih[2q+e,:]) + b_ih + b_hh) * SCALE
// Lane-major layout so the scan's per-lane reads are contiguous over t.
// Also writes the lengths tail of d_out and zeroes the progress flags used by
// the fused producer/consumer kernel (stream order guarantees visibility).
// ---------------------------------------------------------------------------
__global__ __launch_bounds__(256) void k_xproj(
    const int* __restrict__ X, const int* __restrict__ lengths,
    const float* __restrict__ emb, const float* __restrict__ W_ih,
    const float* __restrict__ b_ih, const float* __restrict__ b_hh,
    float* __restrict__ xpT, float* __restrict__ out_tail,
    int* __restrict__ prog)
{
    int r = blockIdx.x * 256 + threadIdx.x;
    if (r < Bz * Tz) {
        int v = X[r];
        const float4* e4 = (const float4*)(emb + (size_t)v * Hz);
        float4 ea = e4[0], eb = e4[1];
        float res[8];
#pragma unroll
        for (int i = 0; i < 8; ++i) {
            const float* w = W_ih + i * 8;  // uniform address -> scalar loads
            float a = b_ih[i] + b_hh[i];
            a = fmaf(ea.x, w[0], a); a = fmaf(ea.y, w[1], a);
            a = fmaf(ea.z, w[2], a); a = fmaf(ea.w, w[3], a);
            a = fmaf(eb.x, w[4], a); a = fmaf(eb.y, w[5], a);
            a = fmaf(eb.z, w[6], a); a = fmaf(eb.w, w[7], a);
            res[i] = a * SCALE;
        }
        int b = r >> 11, t = r & 2047;
#pragma unroll
        for (int q = 0; q < 4; ++q) {
            *(float2*)(xpT + ((size_t)(b * 4 + q) * Tz + t) * 2) =
                make_float2(res[2 * q], res[2 * q + 1]);
        }
    }
    if (r < Bz) out_tail[r] = (float)lengths[r];
    if (prog != nullptr && r < 4) prog[r] = 0;  // per-wave progress counters
}

// ---------------------------------------------------------------------------
// Scan: h = tanh(xp_t + W_hh h), 4 lanes per batch, lane q holds h[2q],h[2q+1].
// Cross-lane h all-gather via DPP quad_perm rotations. Dot product regrouped
// as a 4-partial tree (critical path ~16cy vs 32cy for the linear chain).
// Weights/xp pre-scaled by 2/ln2 so tanh starts directly at exp2.
// ---------------------------------------------------------------------------
#define QROT(x, CTRL) \
    __int_as_float(__builtin_amdgcn_update_dpp(0, __float_as_int(x), (CTRL), 0xF, 0xF, true))
// quad_perm ctrl: rot1=[1,2,3,0]=0x39, rot2=[2,3,0,1]=0x4E, rot3=[3,0,1,2]=0x93

__device__ __forceinline__ float fast_tanh_pre(float m) {
    // input m = 2*a/ln2 already; tanh(a) = (e-1)/(e+1), e = 2^m.
    m = fminf(m, 126.0f);  // upper clamp only: exp2(-big)->0 gives -1 exactly
#if __has_builtin(__builtin_amdgcn_exp2f)
    float e = __builtin_amdgcn_exp2f(m);
#else
    float e = exp2f(m);
#endif
#if __has_builtin(__builtin_amdgcn_rcpf)
    return (e - 1.0f) * __builtin_amdgcn_rcpf(e + 1.0f);
#else
    return (e - 1.0f) / (e + 1.0f);
#endif
}

#define STEP(xx, yy, toff) do { \
    float p1x = QROT(h0, 0x39), p1y = QROT(h1, 0x39); \
    float p2x = QROT(h0, 0x4E), p2y = QROT(h1, 0x4E); \
    float p3x = QROT(h0, 0x93), p3y = QROT(h1, 0x93); \
    float s0a = fmaf(h1, w0[1], fmaf(h0, w0[0], (xx))); \
    float s0b = fmaf(h1, w1[1], fmaf(h0, w1[0], (yy))); \
    float s1a = fmaf(p1y, w0[3], p1x * w0[2]); \
    float s1b = fmaf(p1y, w1[3], p1x * w1[2]); \
    float s2a = fmaf(p2y, w0[5], p2x * w0[4]); \
    float s2b = fmaf(p2y, w1[5], p2x * w1[4]); \
    float s3a = fmaf(p3y, w0[7], p3x * w0[6]); \
    float s3b = fmaf(p3y, w1[7], p3x * w1[6]); \
    h0 = fast_tanh_pre((s0a + s1a) + (s2a + s3a)); \
    h1 = fast_tanh_pre((s0b + s1b) + (s2b + s3b)); \
    f32x2 hv = { h0, h1 }; \
    __builtin_nontemporal_store(hv, (f32x2*)(hs_base + (size_t)(toff) * 8)); \
} while (0)

__device__ __forceinline__ void scan_run(
    const float* __restrict__ xpT, const float* __restrict__ W_hh,
    float* __restrict__ hs, int b, int q, int* prog, int wv)
{
    int i0 = 2 * q, i1 = 2 * q + 1;
    // Weights in quad-rotation order: term r uses h-pair from lane (q+r)&3.
    float w0[8], w1[8];
#pragma unroll
    for (int r = 0; r < 4; ++r) {
        int jj = ((q + r) & 3) * 2;
        w0[2 * r]     = W_hh[i0 * 8 + jj]     * SCALE;
        w0[2 * r + 1] = W_hh[i0 * 8 + jj + 1] * SCALE;
        w1[2 * r]     = W_hh[i1 * 8 + jj]     * SCALE;
        w1[2 * r + 1] = W_hh[i1 * 8 + jj + 1] * SCALE;
    }

    const float4* xp4 = (const float4*)(xpT + (size_t)(b * 4 + q) * Tz * 2);
    float* hs_base = hs + (size_t)b * Tz * 8 + 2 * q;

    float h0 = 0.0f, h1 = 0.0f;
    float4 c0 = xp4[0], c1 = xp4[1], c2 = xp4[2], c3 = xp4[3];

    for (int g = 0; g < Tz / 8; ++g) {
        // prefetch next chunk (reads 64B past the end on the last iteration,
        // which lands in the hs region of the workspace -- harmless)
        float4 n0 = xp4[4 * g + 4], n1 = xp4[4 * g + 5];
        float4 n2 = xp4[4 * g + 6], n3 = xp4[4 * g + 7];
        int t0 = g * 8;
        STEP(c0.x, c0.y, t0 + 0); STEP(c0.z, c0.w, t0 + 1);
        STEP(c1.x, c1.y, t0 + 2); STEP(c1.z, c1.w, t0 + 3);
        STEP(c2.x, c2.y, t0 + 4); STEP(c2.z, c2.w, t0 + 5);
        STEP(c3.x, c3.y, t0 + 6); STEP(c3.z, c3.w, t0 + 7);
        c0 = n0; c1 = n1; c2 = n2; c3 = n3;
        // publish chunk (128 steps) completion: release makes this wave's hs
        // stores (nt -> little dirty L2 to write back) device-visible.
        if (prog != nullptr && (g & 15) == 15) {
            if ((threadIdx.x & 63) == 0)
                __hip_atomic_store(&prog[wv], (g >> 4) + 1,
                                   __ATOMIC_RELEASE, __HIP_MEMORY_SCOPE_AGENT);
        }
    }
}

// Fallback standalone scan (used only if workspace has no room for flags).
__global__ __launch_bounds__(64) void k_scan(
    const float* __restrict__ xpT, const float* __restrict__ W_hh,
    float* __restrict__ hs)
{
    int lane = threadIdx.x;
    scan_run(xpT, W_hh, hs, blockIdx.x * 16 + (lane >> 2), lane & 3, nullptr, 0);
}

// ---------------------------------------------------------------------------
// Fused producer/consumer kernel.
// Block 0: the 4 scan waves (16 batches each), publishing prog[wv] per 128-step
//          chunk. Blocks 1..255: output projection; block k consumes tiles
//          tau = k-1, k-1+255, ... (tau = chunk*64 + b) so each chunk's 64
//          tiles land on 64 distinct blocks -> chunk drain keeps pace with
//          production while later blocks sleep-wait. Grid=256 <= #CUs, so all
//          blocks are co-resident: spin-wait cannot deadlock the producer.
// ---------------------------------------------------------------------------
__global__ __launch_bounds__(256) void k_fused(
    const float* __restrict__ xpT, const float* __restrict__ W_hh,
    float* __restrict__ hs, const int* __restrict__ lengths,
    const float* __restrict__ W_out, const float* __restrict__ b_out,
    float* __restrict__ out, int* __restrict__ prog)
{
    __shared__ float4 sh4[256];  // 128 rows x 8 floats
    int tid = threadIdx.x;

    if (blockIdx.x == 0) {  // producer
        int lane = tid & 63, wv = tid >> 6;
        scan_run(xpT, W_hh, hs, wv * 16 + (lane >> 2), lane & 3, prog, wv);
        return;
    }

    int k0 = blockIdx.x - 1;  // 0..254

    // hoist per-thread W_out rows into registers (survive cache invalidates)
    float w[4][8], bo[4];
    if (tid < Oz / 4) {
#pragma unroll
        for (int k = 0; k < 4; ++k) {
            const float4* wr = (const float4*)(W_out + (size_t)(tid * 4 + k) * 8);
            float4 wa = wr[0], wb = wr[1];
            w[k][0] = wa.x; w[k][1] = wa.y; w[k][2] = wa.z; w[k][3] = wa.w;
            w[k][4] = wb.x; w[k][5] = wb.y; w[k][6] = wb.z; w[k][7] = wb.w;
            bo[k] = b_out[tid * 4 + k];
        }
    }

    for (int tau = k0; tau < (Bz * Tz) / 128; tau += 255) {
        int c = tau >> 6;   // time chunk (128 steps)
        int b = tau & 63;   // batch
        if (tid == 0) {
            while (__hip_atomic_load(&prog[b >> 4], __ATOMIC_ACQUIRE,
                                     __HIP_MEMORY_SCOPE_AGENT) <= c)
                __builtin_amdgcn_s_sleep(8);
        }
        __syncthreads();  // flag observed; acquire ordered the hs reads below

        int r0 = b * Tz + c * 128;  // global row = b*T + t0
        {   // cooperative stage of 128 hs rows, applying the length mask
            int t = c * 128 + (tid >> 1);
            float4 v = ((const float4*)hs)[(size_t)r0 * 2 + tid];
            if (t >= lengths[b]) v = make_float4(0.f, 0.f, 0.f, 0.f);
            sh4[tid] = v;
        }
        __syncthreads();

        if (tid < Oz / 4) {  // 250 active threads
            for (int rr = 0; rr < 128; ++rr) {
                float4 ha = sh4[rr * 2], hb = sh4[rr * 2 + 1];  // LDS broadcast
                float r[4];
#pragma unroll
                for (int k = 0; k < 4; ++k) {
                    float a = bo[k];
                    a = fmaf(ha.x, w[k][0], a); a = fmaf(ha.y, w[k][1], a);
                    a = fmaf(ha.z, w[k][2], a); a = fmaf(ha.w, w[k][3], a);
                    a = fmaf(hb.x, w[k][4], a); a = fmaf(hb.y, w[k][5], a);
                    a = fmaf(hb.z, w[k][6], a); a = fmaf(hb.w, w[k][7], a);
                    r[k] = a;
                }
                f32x4 acc = { r[0], r[1], r[2], r[3] };
                __builtin_nontemporal_store(
                    acc, (f32x4*)(out + (size_t)(r0 + rr) * Oz) + tid);
            }
        }
        __syncthreads();  // LDS reused next tile
    }
}

// ---------------------------------------------------------------------------
// Fallback output projection (old k_out), used only when flags don't fit.
// ---------------------------------------------------------------------------
__global__ __launch_bounds__(256) void k_out(
    const float* __restrict__ hs, const int* __restrict__ lengths,
    const float* __restrict__ W_out, const float* __restrict__ b_out,
    float* __restrict__ out)
{
    __shared__ float4 sh4[256];
    int tid = threadIdx.x;
    int r0 = blockIdx.x * 128;

    {
        int row = r0 + (tid >> 1);
        int b = row >> 11, t = row & 2047;
        float4 v = ((const float4*)hs)[(size_t)r0 * 2 + tid];
        if (t >= lengths[b]) v = make_float4(0.f, 0.f, 0.f, 0.f);
        sh4[tid] = v;
    }
    __syncthreads();

    if (tid >= Oz / 4) return;

    float w[4][8];
    float bo[4];
#pragma unroll
    for (int k = 0; k < 4; ++k) {
        const float4* wr = (const float4*)(W_out + (size_t)(tid * 4 + k) * 8);
        float4 wa = wr[0], wb = wr[1];
        w[k][0] = wa.x; w[k][1] = wa.y; w[k][2] = wa.z; w[k][3] = wa.w;
        w[k][4] = wb.x; w[k][5] = wb.y; w[k][6] = wb.z; w[k][7] = wb.w;
        bo[k] = b_out[tid * 4 + k];
    }

    for (int rr = 0; rr < 128; ++rr) {
        float4 ha = sh4[rr * 2], hb = sh4[rr * 2 + 1];
        float r[4];
#pragma unroll
        for (int k = 0; k < 4; ++k) {
            float a = bo[k];
            a = fmaf(ha.x, w[k][0], a); a = fmaf(ha.y, w[k][1], a);
            a = fmaf(ha.z, w[k][2], a); a = fmaf(ha.w, w[k][3], a);
            a = fmaf(hb.x, w[k][4], a); a = fmaf(hb.y, w[k][5], a);
            a = fmaf(hb.z, w[k][6], a); a = fmaf(hb.w, w[k][7], a);
            r[k] = a;
        }
        f32x4 acc = { r[0], r[1], r[2], r[3] };
        __builtin_nontemporal_store(
            acc, (f32x4*)(out + (size_t)(r0 + rr) * Oz) + tid);
    }
}

// ---------------------------------------------------------------------------
extern "C" void kernel_launch(void* const* d_in, const int* in_sizes, int n_in,
                              void* d_out, int out_size, void* d_ws, size_t ws_size,
                              hipStream_t stream)
{
    const int*   X       = (const int*)d_in[0];
    const int*   lengths = (const int*)d_in[1];
    const float* emb     = (const float*)d_in[2];
    const float* W_ih    = (const float*)d_in[3];
    const float* W_hh    = (const float*)d_in[4];
    const float* b_ih    = (const float*)d_in[5];
    const float* b_hh    = (const float*)d_in[6];
    const float* W_out   = (const float*)d_in[7];
    const float* b_out   = (const float*)d_in[8];

    float* out   = (float*)d_out;
    float* xpT   = (float*)d_ws;                     // 4 MB (lane-major x_proj)
    float* hs    = xpT + (size_t)Bz * Tz * Hz;       // 4 MB

    // lengths tail of d_out (output 1 of the tuple)
    float* out_tail = out + (size_t)Bz * Tz * Oz;

    size_t base = (size_t)Bz * Tz * Hz * 4 * 2;      // 8 MB (xpT + hs)
    bool fused = (ws_size >= base + 64);
    int* prog = fused ? (int*)((char*)d_ws + base) : nullptr;

    k_xproj<<<(Bz * Tz + 255) / 256, 256, 0, stream>>>(X, lengths, emb, W_ih,
                                                       b_ih, b_hh, xpT, out_tail,
                                                       prog);
    if (fused) {
        k_fused<<<256, 256, 0, stream>>>(xpT, W_hh, hs, lengths, W_out, b_out,
                                         out, prog);
    } else {
        k_scan<<<Bz / 16, 64, 0, stream>>>(xpT, W_hh, hs);
        k_out<<<(Bz * Tz) / 128, 256, 0, stream>>>(hs, lengths, W_out, b_out, out);
    }
}

// Round 2
// 735.850 us; speedup vs baseline: 3.0141x; 3.0141x over previous
//
#include <hip/hip_runtime.h>
#include <cstdint>
#include <cstddef>

// Problem dims (RNN_57208964382771)
#define Bz 64
#define Tz 2048
#define Hz 8
#define Vz 1000
#define Oz 1000

// 2/ln2 — folded into W_hh and x_proj so fast_tanh skips its input scaling mul
#define SCALE 2.885390081777927f
// xp clamp: 126 - 8*0.3536*SCALE (max |h|-contribution) ~= 117.8 -> 117
#define XPCLAMP 117.0f

typedef float f32x4 __attribute__((ext_vector_type(4)));

// ---------------------------------------------------------------------------
// Kernel 1: xpT[b][q][t][e] = clamp((dot(emb[X[b,t]], W_ih[2q+e,:]) + b_ih +
//           b_hh) * SCALE, <= XPCLAMP)
// Lane-major layout so the scan's per-lane reads are contiguous over t.
// Also writes the lengths tail of d_out (output 1 of the tuple, as float).
// ---------------------------------------------------------------------------
__global__ __launch_bounds__(256) void k_xproj(
    const int* __restrict__ X, const int* __restrict__ lengths,
    const float* __restrict__ emb, const float* __restrict__ W_ih,
    const float* __restrict__ b_ih, const float* __restrict__ b_hh,
    float* __restrict__ xpT, float* __restrict__ out_tail)
{
    int r = blockIdx.x * 256 + threadIdx.x;
    if (r < Bz * Tz) {
        int v = X[r];
        const float4* e4 = (const float4*)(emb + (size_t)v * Hz);
        float4 ea = e4[0], eb = e4[1];
        float res[8];
#pragma unroll
        for (int i = 0; i < 8; ++i) {
            const float* w = W_ih + i * 8;  // uniform address -> scalar loads
            float a = b_ih[i] + b_hh[i];
            a = fmaf(ea.x, w[0], a); a = fmaf(ea.y, w[1], a);
            a = fmaf(ea.z, w[2], a); a = fmaf(ea.w, w[3], a);
            a = fmaf(eb.x, w[4], a); a = fmaf(eb.y, w[5], a);
            a = fmaf(eb.z, w[6], a); a = fmaf(eb.w, w[7], a);
            res[i] = fminf(a * SCALE, XPCLAMP);  // upper clamp moved off scan path
        }
        int b = r >> 11, t = r & 2047;
#pragma unroll
        for (int q = 0; q < 4; ++q) {
            *(float2*)(xpT + ((size_t)(b * 4 + q) * Tz + t) * 2) =
                make_float2(res[2 * q], res[2 * q + 1]);
        }
    }
    if (r < Bz) out_tail[r] = (float)lengths[r];
}

// ---------------------------------------------------------------------------
// Kernel 2: sequential scan  h = tanh(xp_t + W_hh h)   (biases folded into xp,
// everything pre-scaled by 2/ln2 so tanh starts directly at exp2).
// 4 lanes per batch; lane q holds h[2q], h[2q+1]. Cross-lane h all-gather via
// DPP quad_perm rotations. Dot product tree-reduced (dep chain ~16cy).
//
// hs layout is T-MAJOR: hs[t][b][8]. Per step each wave stores 16 batches x
// 32B = 512 CONTIGUOUS bytes (full 64B lines -> no write-allocate RMW, cheap
// L2 retirement). This was the round-0/round-1 scan bottleneck: batch-major
// hs made every step 16 scattered partial-line stores.
// ---------------------------------------------------------------------------
#define QROT(x, CTRL) \
    __int_as_float(__builtin_amdgcn_update_dpp(0, __float_as_int(x), (CTRL), 0xF, 0xF, true))
// quad_perm ctrl: rot1=[1,2,3,0]=0x39, rot2=[2,3,0,1]=0x4E, rot3=[3,0,1,2]=0x93

__device__ __forceinline__ float fast_tanh_pre(float m) {
    // input m = 2*a/ln2 already, upper-bounded < 126 by the xproj clamp.
    // tanh(a) = (e-1)/(e+1), e = 2^m. For very negative m, exp2 -> 0 -> -1.
#if __has_builtin(__builtin_amdgcn_exp2f)
    float e = __builtin_amdgcn_exp2f(m);
#else
    float e = exp2f(m);
#endif
#if __has_builtin(__builtin_amdgcn_rcpf)
    return (e - 1.0f) * __builtin_amdgcn_rcpf(e + 1.0f);
#else
    return (e - 1.0f) / (e + 1.0f);
#endif
}

#define STEP(xx, yy, toff) do { \
    float p1x = QROT(h0, 0x39), p1y = QROT(h1, 0x39); \
    float p2x = QROT(h0, 0x4E), p2y = QROT(h1, 0x4E); \
    float p3x = QROT(h0, 0x93), p3y = QROT(h1, 0x93); \
    float s0a = fmaf(h1, w0[1], fmaf(h0, w0[0], (xx))); \
    float s0b = fmaf(h1, w1[1], fmaf(h0, w1[0], (yy))); \
    float s1a = fmaf(p1y, w0[3], p1x * w0[2]); \
    float s1b = fmaf(p1y, w1[3], p1x * w1[2]); \
    float s2a = fmaf(p2y, w0[5], p2x * w0[4]); \
    float s2b = fmaf(p2y, w1[5], p2x * w1[4]); \
    float s3a = fmaf(p3y, w0[7], p3x * w0[6]); \
    float s3b = fmaf(p3y, w1[7], p3x * w1[6]); \
    h0 = fast_tanh_pre((s0a + s1a) + (s2a + s3a)); \
    h1 = fast_tanh_pre((s0b + s1b) + (s2b + s3b)); \
    *(float2*)(hs_base + (size_t)(toff) * (Bz * Hz)) = make_float2(h0, h1); \
} while (0)

__global__ __launch_bounds__(64) void k_scan(
    const float* __restrict__ xpT, const float* __restrict__ W_hh,
    float* __restrict__ hs)
{
    int lane = threadIdx.x;                 // 0..63, one wave per block
    int b = blockIdx.x * 16 + (lane >> 2);  // 16 batches per wave
    int q = lane & 3;
    int i0 = 2 * q, i1 = 2 * q + 1;

    // Weights in quad-rotation order: term r uses h-pair from lane (q+r)&3.
    float w0[8], w1[8];
#pragma unroll
    for (int r = 0; r < 4; ++r) {
        int jj = ((q + r) & 3) * 2;
        w0[2 * r]     = W_hh[i0 * 8 + jj]     * SCALE;
        w0[2 * r + 1] = W_hh[i0 * 8 + jj + 1] * SCALE;
        w1[2 * r]     = W_hh[i1 * 8 + jj]     * SCALE;
        w1[2 * r + 1] = W_hh[i1 * 8 + jj + 1] * SCALE;
    }

    const float4* xp4 = (const float4*)(xpT + (size_t)(b * 4 + q) * Tz * 2);
    float* hs_base = hs + (size_t)b * Hz + 2 * q;   // t-major: + t*(Bz*Hz)

    float h0 = 0.0f, h1 = 0.0f;
    float4 c0 = xp4[0], c1 = xp4[1], c2 = xp4[2], c3 = xp4[3];

    for (int c = 0; c < Tz / 8; ++c) {
        // prefetch next chunk (reads 64B past the end on the last iteration,
        // which lands in the hs region of the workspace -- harmless)
        float4 n0 = xp4[4 * c + 4], n1 = xp4[4 * c + 5];
        float4 n2 = xp4[4 * c + 6], n3 = xp4[4 * c + 7];
        int t0 = c * 8;
        STEP(c0.x, c0.y, t0 + 0); STEP(c0.z, c0.w, t0 + 1);
        STEP(c1.x, c1.y, t0 + 2); STEP(c1.z, c1.w, t0 + 3);
        STEP(c2.x, c2.y, t0 + 4); STEP(c2.z, c2.w, t0 + 5);
        STEP(c3.x, c3.y, t0 + 6); STEP(c3.z, c3.w, t0 + 7);
        c0 = n0; c1 = n1; c2 = n2; c3 = n3;
    }
}

// ---------------------------------------------------------------------------
// Kernel 3: logits[b, t, o] = sum_i hs_masked[t,b,i] * W_out[o,i] + b_out[o]
// Each block owns 2 t-values x all 64 batches = 128 rows; with t-major hs the
// whole 4KB tile is one CONTIGUOUS stretch (perfectly coalesced stage).
// Length mask applied during LDS staging. Nontemporal float4 stores for the
// 524 MB logits stream (full-line streaming writes).
// ---------------------------------------------------------------------------
__global__ __launch_bounds__(256) void k_out(
    const float* __restrict__ hs, const int* __restrict__ lengths,
    const float* __restrict__ W_out, const float* __restrict__ b_out,
    float* __restrict__ out)
{
    __shared__ float4 sh4[256];  // 128 rows x 8 floats; row rr = tt*64 + b
    int tid = threadIdx.x;
    int t0 = blockIdx.x * 2;

    // cooperative stage: hs float4 index t0*128 + tid (4KB contiguous)
    {
        float4 v = ((const float4*)hs)[(size_t)t0 * 128 + tid];
        int tt = tid >> 7, b = (tid & 127) >> 1;
        if (t0 + tt >= lengths[b]) v = make_float4(0.f, 0.f, 0.f, 0.f);
        sh4[tid] = v;
    }
    __syncthreads();

    if (tid >= Oz / 4) return;  // 250 active threads

    float w[4][8];
    float bo[4];
#pragma unroll
    for (int k = 0; k < 4; ++k) {
        const float4* wr = (const float4*)(W_out + (size_t)(tid * 4 + k) * 8);
        float4 wa = wr[0], wb = wr[1];
        w[k][0] = wa.x; w[k][1] = wa.y; w[k][2] = wa.z; w[k][3] = wa.w;
        w[k][4] = wb.x; w[k][5] = wb.y; w[k][6] = wb.z; w[k][7] = wb.w;
        bo[k] = b_out[tid * 4 + k];
    }

    for (int rr = 0; rr < 128; ++rr) {
        float4 ha = sh4[rr * 2], hb = sh4[rr * 2 + 1];  // LDS broadcast reads
        int tt = rr >> 6, b = rr & 63;
        float r[4];
#pragma unroll
        for (int k = 0; k < 4; ++k) {
            float a = bo[k];
            a = fmaf(ha.x, w[k][0], a); a = fmaf(ha.y, w[k][1], a);
            a = fmaf(ha.z, w[k][2], a); a = fmaf(ha.w, w[k][3], a);
            a = fmaf(hb.x, w[k][4], a); a = fmaf(hb.y, w[k][5], a);
            a = fmaf(hb.z, w[k][6], a); a = fmaf(hb.w, w[k][7], a);
            r[k] = a;
        }
        f32x4 acc = { r[0], r[1], r[2], r[3] };
        __builtin_nontemporal_store(
            acc, (f32x4*)(out + ((size_t)b * Tz + t0 + tt) * Oz) + tid);
    }
}

// ---------------------------------------------------------------------------
extern "C" void kernel_launch(void* const* d_in, const int* in_sizes, int n_in,
                              void* d_out, int out_size, void* d_ws, size_t ws_size,
                              hipStream_t stream)
{
    const int*   X       = (const int*)d_in[0];
    const int*   lengths = (const int*)d_in[1];
    const float* emb     = (const float*)d_in[2];
    const float* W_ih    = (const float*)d_in[3];
    const float* W_hh    = (const float*)d_in[4];
    const float* b_ih    = (const float*)d_in[5];
    const float* b_hh    = (const float*)d_in[6];
    const float* W_out   = (const float*)d_in[7];
    const float* b_out   = (const float*)d_in[8];

    float* out   = (float*)d_out;
    float* xpT   = (float*)d_ws;                     // 4 MB (lane-major x_proj)
    float* hs    = xpT + (size_t)Bz * Tz * Hz;       // 4 MB (t-major hidden states)

    // lengths tail of d_out (output 1 of the tuple)
    float* out_tail = out + (size_t)Bz * Tz * Oz;

    // Kernel boundaries provide the implicit agent-scope release/acquire
    // (L2 writeback + invalidate) needed for cross-XCD hs visibility.
    k_xproj<<<(Bz * Tz + 255) / 256, 256, 0, stream>>>(X, lengths, emb, W_ih,
                                                       b_ih, b_hh, xpT, out_tail);
    k_scan<<<Bz / 16, 64, 0, stream>>>(xpT, W_hh, hs);
    k_out<<<Tz / 2, 256, 0, stream>>>(hs, lengths, W_out, b_out, out);
}